// Round 8
// baseline (128.221 us; speedup 1.0000x reference)
//
#include <hip/hip_runtime.h>
#include <math.h>

#define B_SZ 1024
#define Z_DIM 512
#define A_DIM 8
#define AH 64
#define ZH 512
#define NNEG 99
#define INV_T 10.0f

typedef __attribute__((ext_vector_type(8))) short short8;   // 8 bf16 (16 B)
typedef __attribute__((ext_vector_type(4))) float f32x4;

// fp32 -> bf16 round-to-nearest-even (unbiased; rel err <= 2^-9)
__device__ __forceinline__ short bf16rn(float x) {
    unsigned u = __float_as_uint(x);
    u += 0x7fffu + ((u >> 16) & 1u);
    return (short)(u >> 16);
}
__device__ __forceinline__ void cvt8rn(float4 x0, float4 x1, short8& h) {
    h[0] = bf16rn(x0.x); h[1] = bf16rn(x0.y); h[2] = bf16rn(x0.z); h[3] = bf16rn(x0.w);
    h[4] = bf16rn(x1.x); h[5] = bf16rn(x1.y); h[6] = bf16rn(x1.z); h[7] = bf16rn(x1.w);
}

// XOR-swizzled 16B-unit index into a [64 rows][8 units] bf16 tile (no padding).
__device__ __forceinline__ int sw(int m, int kb) { return m * 8 + (kb ^ (m & 7)); }

// ---------------------------------------------------------------------------
// prep: blocks [0,72) transpose W1 [576][512] -> W1T [512][576];
//       blocks [72,88) compute ha = relu(actions@Wa+ba)  [1024][64];
//       block 0 resets cnt.
__global__ __launch_bounds__(256) void prep_kernel(
    const float* __restrict__ W1, const float* __restrict__ actions,
    const float* __restrict__ Wa, const float* __restrict__ ba,
    float* __restrict__ W1T, float* __restrict__ ha, unsigned* __restrict__ cnt)
{
    const int id = blockIdx.x, tid = threadIdx.x;
    if (id == 0 && tid == 0) atomicExch(cnt, 0u);
    if (id < 72) {
        __shared__ float L[64][68];
        int kt = id >> 3, nt = id & 7;
#pragma unroll
        for (int i = 0; i < 4; ++i) {
            int f = tid + i * 256;
            int r = f >> 4, c4 = (f & 15) << 2;
            *(float4*)&L[r][c4] = *(const float4*)&W1[(kt * 64 + r) * 512 + nt * 64 + c4];
        }
        __syncthreads();
#pragma unroll
        for (int i = 0; i < 4; ++i) {
            int f = tid + i * 256;
            int r = f >> 4, c4 = (f & 15) << 2;
            float4 o = {L[c4][r], L[c4 + 1][r], L[c4 + 2][r], L[c4 + 3][r]};
            *(float4*)&W1T[(nt * 64 + r) * 576 + kt * 64 + c4] = o;
        }
    } else if (id < 88) {
        __shared__ float sWa[A_DIM * 64];
        __shared__ float sba[64];
        __shared__ float sact[64][A_DIM];
        int j0 = (id - 72) * 64;
        for (int i = tid; i < A_DIM * 64; i += 256) sWa[i] = Wa[i];
        if (tid < 64) sba[tid] = ba[tid];
        for (int i = tid; i < 64 * A_DIM; i += 256) (&sact[0][0])[i] = actions[j0 * A_DIM + i];
        __syncthreads();
        int r = tid >> 2, c0 = (tid & 3) * 16;
        float o[16];
#pragma unroll
        for (int c = 0; c < 16; ++c) o[c] = sba[c0 + c];
#pragma unroll
        for (int k = 0; k < A_DIM; ++k) {
            float a = sact[r][k];
#pragma unroll
            for (int c = 0; c < 16; ++c) o[c] += a * sWa[k * 64 + c0 + c];
        }
#pragma unroll
        for (int c = 0; c < 16; c += 4) {
            float4 v4 = {fmaxf(o[c], 0.f), fmaxf(o[c + 1], 0.f),
                         fmaxf(o[c + 2], 0.f), fmaxf(o[c + 3], 0.f)};
            *(float4*)&ha[(j0 + r) * 64 + c0 + c] = v4;
        }
    }
}

// ---------------------------------------------------------------------------
// Uniform NT MFMA GEMM, 640 blocks, plain bf16 (RN conversion at staging):
//   seg0 [  0,256): sim = z_next @ z_next_hat^T [1024x1024 K=512]
//   seg1 [256,384): u   = z @ W1T[:, :512]^T+b1 [1024x512  K=512]
//   seg2 [384,512): v   = z_next @ W2^T         [1024x512  K=512]
//   seg3 [512,640): g   = ha @ W1T[:,512:]^T    [1024x512  K=64]
__global__ __launch_bounds__(256) void mm_kernel(
    const float* __restrict__ z, const float* __restrict__ z_next,
    const float* __restrict__ z_next_hat, const float* __restrict__ W1T,
    const float* __restrict__ b1, const float* __restrict__ W2,
    const float* __restrict__ ha,
    float* __restrict__ sim, float* __restrict__ u, float* __restrict__ v,
    float* __restrict__ g)
{
    __shared__ short Ah[4096], Bh[4096];   // 16 KB

    const int id = blockIdx.x;
    const int tid = threadIdx.x;

    const float* Aop; const float* Bop; const float* bias = nullptr;
    float* C; int N, K, lda, ldb, bm0, bn0;
    if (id < 256) {
        int t = id; bn0 = (t & 15) * 64; bm0 = (t >> 4) * 64;
        Aop = z_next; lda = 512; Bop = z_next_hat; ldb = 512;
        C = sim; N = 1024; K = 512;
    } else if (id < 384) {
        int t = id - 256; bn0 = (t & 7) * 64; bm0 = (t >> 3) * 64;
        Aop = z; lda = 512; Bop = W1T; ldb = 576;
        C = u; N = 512; K = 512; bias = b1;
    } else if (id < 512) {
        int t = id - 384; bn0 = (t & 7) * 64; bm0 = (t >> 3) * 64;
        Aop = z_next; lda = 512; Bop = W2; ldb = 512;
        C = v; N = 512; K = 512;
    } else {
        int t = id - 512; bn0 = (t & 7) * 64; bm0 = (t >> 3) * 64;
        Aop = ha; lda = 64; Bop = W1T + 512; ldb = 576;
        C = g; N = 512; K = 64;
    }

    const int lane = tid & 63, wv = tid >> 6;
    const int lm = lane & 15, lq = lane >> 4;
    const int wm = (wv >> 1) * 32, wn = (wv & 1) * 32;
    const int sr = tid >> 2, sq = tid & 3;     // staging: row, 16-float quarter
    short8* Ah8 = (short8*)Ah; short8* Bh8 = (short8*)Bh;
    f32x4 acc[2][2] = {};

    for (int k0 = 0; k0 < K; k0 += 64) {
        {   // A: 16 consecutive floats of row sr -> units 2sq, 2sq+1
            const float* base = &Aop[(bm0 + sr) * lda + k0 + sq * 16];
            float4 x0 = *(const float4*)(base + 0), x1 = *(const float4*)(base + 4);
            float4 x2 = *(const float4*)(base + 8), x3 = *(const float4*)(base + 12);
            short8 h;
            cvt8rn(x0, x1, h); Ah8[sw(sr, 2 * sq)] = h;
            cvt8rn(x2, x3, h); Ah8[sw(sr, 2 * sq + 1)] = h;
        }
        {   // B: same, NT layout
            const float* base = &Bop[(bn0 + sr) * ldb + k0 + sq * 16];
            float4 x0 = *(const float4*)(base + 0), x1 = *(const float4*)(base + 4);
            float4 x2 = *(const float4*)(base + 8), x3 = *(const float4*)(base + 12);
            short8 h;
            cvt8rn(x0, x1, h); Bh8[sw(sr, 2 * sq)] = h;
            cvt8rn(x2, x3, h); Bh8[sw(sr, 2 * sq + 1)] = h;
        }
        __syncthreads();
#pragma unroll
        for (int kk = 0; kk < 64; kk += 32) {
            int kbi = (kk >> 3) + lq;
            short8 ah[2], bh[2];
#pragma unroll
            for (int i = 0; i < 2; ++i) {
                ah[i] = Ah8[sw(wm + i * 16 + lm, kbi)];
                bh[i] = Bh8[sw(wn + i * 16 + lm, kbi)];
            }
#pragma unroll
            for (int i = 0; i < 2; ++i)
#pragma unroll
                for (int j = 0; j < 2; ++j)
                    acc[i][j] = __builtin_amdgcn_mfma_f32_16x16x32_bf16(ah[i], bh[j], acc[i][j], 0, 0, 0);
        }
        __syncthreads();
    }
    // epilogue: C layout col=lane&15, row=(lane>>4)*4+reg
#pragma unroll
    for (int i = 0; i < 2; ++i)
#pragma unroll
        for (int j = 0; j < 2; ++j) {
            int n = bn0 + wn + j * 16 + lm;
            float bb = bias ? bias[n] : 0.0f;
#pragma unroll
            for (int r = 0; r < 4; ++r) {
                int m = bm0 + wm + i * 16 + lq * 4 + r;
                C[m * N + n] = acc[i][j][r] + bb;
            }
        }
}

// ---------------------------------------------------------------------------
// 256 blocks x 256 threads, 4 rows/block (1 row per wave). g-rows staged to
// LDS once per block in batches of 8, DOUBLE-BUFFERED: batch it+1 prefetched
// into registers while batch it is consumed (one barrier per iteration).
// Phase 2: per-wave softmax/rank. Last block finalizes.
__global__ __launch_bounds__(256) void row2_kernel(
    const float* __restrict__ sim, const float* __restrict__ u,
    const float* __restrict__ v, const float* __restrict__ g,
    const float* __restrict__ z, const float* __restrict__ z_next,
    const float* __restrict__ b2,
    float* __restrict__ pw, unsigned* __restrict__ cnt, float* __restrict__ out)
{
    const int blk = blockIdx.x;
    const int tid = threadIdx.x;
    const int w = tid >> 6, lane = tid & 63;
    const int b = blk * 4 + w;
    __shared__ float gbuf[2][8][512];     // 32 KB, double-buffered
    __shared__ float rn[4][100];
    __shared__ float sacc[4][4];
    __shared__ float red[256];
    __shared__ int sdone;

    float4 ua = *(const float4*)&u[b * 512 + lane * 4];
    float4 ub = *(const float4*)&u[b * 512 + 256 + lane * 4];
    float4 va = *(const float4*)&v[b * 512 + lane * 4];
    float4 vb = *(const float4*)&v[b * 512 + 256 + lane * 4];

    // c0 = (z[b]+b2) . z_next[b] (per-wave, lane 0 holds result -> broadcast)
    float p;
    {
        float4 za = *(const float4*)&z[b * 512 + lane * 4];
        float4 zb = *(const float4*)&z[b * 512 + 256 + lane * 4];
        float4 na = *(const float4*)&z_next[b * 512 + lane * 4];
        float4 nb = *(const float4*)&z_next[b * 512 + 256 + lane * 4];
        float4 ca = *(const float4*)&b2[lane * 4];
        float4 cb = *(const float4*)&b2[256 + lane * 4];
        p  = (za.x + ca.x) * na.x + (za.y + ca.y) * na.y + (za.z + ca.z) * na.z + (za.w + ca.w) * na.w;
        p += (zb.x + cb.x) * nb.x + (zb.y + cb.y) * nb.y + (zb.z + cb.z) * nb.z + (zb.w + cb.w) * nb.w;
    }
    for (int off = 32; off; off >>= 1) p += __shfl_down(p, off);
    const float c0 = __shfl(p, 0);

    const int J0 = blk * 4;                // jr = J0 + 1 + idx, idx in [0,104)
    const int prow = tid >> 7;             // reused per-phase below
    (void)prow;

    // prefetch batch 0 into registers
    float4 pre[4];
#pragma unroll
    for (int ph = 0; ph < 4; ++ph) {
        int f4i = tid + ph * 256;
        int row = f4i >> 7, c = f4i & 127;
        int jr = (J0 + 1 + row) & (B_SZ - 1);
        pre[ph] = *(const float4*)&g[jr * 512 + c * 4];
    }

    int pbuf = 0;
    for (int it = 0; it < 13; ++it) {
        // commit prefetched batch to LDS
#pragma unroll
        for (int ph = 0; ph < 4; ++ph) {
            int f4i = tid + ph * 256;
            int row = f4i >> 7, c = f4i & 127;
            *(float4*)&gbuf[pbuf][row][c * 4] = pre[ph];
        }
        __syncthreads();
        // prefetch next batch (no dependency on current compute)
        if (it < 12) {
#pragma unroll
            for (int ph = 0; ph < 4; ++ph) {
                int f4i = tid + ph * 256;
                int row = f4i >> 7, c = f4i & 127;
                int idx = (it + 1) * 8 + row;
                int jr = (J0 + 1 + idx) & (B_SZ - 1);
                pre[ph] = *(const float4*)&g[jr * 512 + c * 4];
            }
        }
        // consume current batch: 8 independent relu-dot chains per wave
        float d[8];
#pragma unroll
        for (int ri = 0; ri < 8; ++ri) {
            float4 g0 = *(const float4*)&gbuf[pbuf][ri][lane * 4];
            float4 g1 = *(const float4*)&gbuf[pbuf][ri][256 + lane * 4];
            float t = 0.0f;
            t += fmaxf(ua.x + g0.x, 0.0f) * va.x;
            t += fmaxf(ua.y + g0.y, 0.0f) * va.y;
            t += fmaxf(ua.z + g0.z, 0.0f) * va.z;
            t += fmaxf(ua.w + g0.w, 0.0f) * va.w;
            t += fmaxf(ub.x + g1.x, 0.0f) * vb.x;
            t += fmaxf(ub.y + g1.y, 0.0f) * vb.y;
            t += fmaxf(ub.z + g1.z, 0.0f) * vb.z;
            t += fmaxf(ub.w + g1.w, 0.0f) * vb.w;
            d[ri] = t;
        }
        for (int off = 32; off; off >>= 1) {
#pragma unroll
            for (int ri = 0; ri < 8; ++ri) d[ri] += __shfl_down(d[ri], off);
        }
        if (lane == 0) {
#pragma unroll
            for (int ri = 0; ri < 8; ++ri) {
                int idx = it * 8 + ri;
                int s1 = idx - w;              // s-1 for this wave's row
                if (idx < 102 && s1 >= 0 && s1 < 99) rn[w][s1] = c0 + d[ri];
            }
        }
        pbuf ^= 1;
        // single barrier per iteration is sufficient with two buffers:
        // nobody writes gbuf[pbuf^1] again until after the NEXT barrier.
    }
    __syncthreads();

    // -------- phase 2: per-wave softmax + rank on row b --------
    float4 sv[4];
#pragma unroll
    for (int i = 0; i < 4; ++i)
        sv[i] = *(const float4*)&sim[b * 1024 + lane * 16 + i * 4];
    float nva = rn[w][lane];
    float nvb = (lane < 35) ? rn[w][lane + 64] : -3.4e38f;
    float diag = sim[b * 1024 + b];

    float m = fmaxf(nva, nvb);
#pragma unroll
    for (int i = 0; i < 4; ++i)
        m = fmaxf(m, fmaxf(fmaxf(sv[i].x, sv[i].y), fmaxf(sv[i].z, sv[i].w)));
    for (int off = 32; off; off >>= 1) m = fmaxf(m, __shfl_xor(m, off));

    float es = 0.0f; int ck = 0;
#pragma unroll
    for (int i = 0; i < 4; ++i) {
        float xs[4] = {sv[i].x, sv[i].y, sv[i].z, sv[i].w};
#pragma unroll
        for (int c = 0; c < 4; ++c) {
            int j = lane * 16 + i * 4 + c;
            float x = xs[c];
            es += __expf((x - m) * INV_T);
            if (x > diag) ck++;
            else if (j < b && x == diag) ck++;   // tie-break: lower index wins
        }
    }
    es += __expf((nva - m) * INV_T);
    if (nva > diag) ck++;
    if (lane < 35) {
        es += __expf((nvb - m) * INV_T);
        if (nvb > diag) ck++;
    }
    for (int off = 32; off; off >>= 1) {
        es += __shfl_down(es, off);
        ck += __shfl_down(ck, off);
    }
    if (lane == 0) {
        float loss_b = (m - diag) * INV_T + logf(es);
        sacc[w][0] = loss_b;
        sacc[w][1] = (ck < 1) ? 1.0f : 0.0f;
        sacc[w][2] = (ck < 3) ? 1.0f : 0.0f;
        sacc[w][3] = (ck < 10) ? 1.0f : 0.0f;
    }
    __syncthreads();
    if (tid == 0) {
#pragma unroll
        for (int c = 0; c < 4; ++c)
            pw[blk * 4 + c] = sacc[0][c] + sacc[1][c] + sacc[2][c] + sacc[3][c];
        __threadfence();
        unsigned old = atomicAdd(cnt, 1u);
        sdone = (old == 255u) ? 1 : 0;
    }
    __syncthreads();
    if (sdone) {
        __threadfence();
        int c = tid & 3;
        float s = 0.0f;
        for (int r = tid >> 2; r < 256; r += 64) s += pw[r * 4 + c];
        red[tid] = s;
        __syncthreads();
        if (tid < 4) {
            float t = 0.0f;
            for (int q = 0; q < 64; ++q) t += red[tid + q * 4];
            out[tid] = t * (1.0f / (float)B_SZ);
        }
    }
}

// ---------------------------------------------------------------------------
extern "C" void kernel_launch(void* const* d_in, const int* in_sizes, int n_in,
                              void* d_out, int out_size, void* d_ws, size_t ws_size,
                              hipStream_t stream) {
    const float* z          = (const float*)d_in[0];
    const float* z_next     = (const float*)d_in[1];
    const float* z_next_hat = (const float*)d_in[2];
    const float* actions    = (const float*)d_in[3];
    const float* Wa         = (const float*)d_in[4];
    const float* ba         = (const float*)d_in[5];
    const float* W1         = (const float*)d_in[6];
    const float* b1         = (const float*)d_in[7];
    const float* W2         = (const float*)d_in[8];
    const float* b2         = (const float*)d_in[9];
    float* out = (float*)d_out;

    float* ws   = (float*)d_ws;
    float* sim  = ws;                          // 1024*1024
    float* u    = sim + B_SZ * B_SZ;           // 1024*512
    float* v    = u + B_SZ * ZH;               // 1024*512
    float* g    = v + B_SZ * ZH;               // 1024*512
    float* W1T  = g + B_SZ * ZH;               // 512*576
    float* ha   = W1T + 512 * 576;             // 1024*64
    float* pw   = ha + B_SZ * AH;              // 256*4
    unsigned* cnt = (unsigned*)(pw + 256 * 4);

    prep_kernel<<<88, 256, 0, stream>>>(W1, actions, Wa, ba, W1T, ha, cnt);
    mm_kernel<<<640, 256, 0, stream>>>(z, z_next, z_next_hat, W1T, b1, W2, ha,
                                       sim, u, v, g);
    row2_kernel<<<256, 256, 0, stream>>>(sim, u, v, g, z, z_next, b2, pw, cnt, out);
}

// Round 9
// 122.727 us; speedup vs baseline: 1.0448x; 1.0448x over previous
//
#include <hip/hip_runtime.h>
#include <math.h>

#define B_SZ 1024
#define Z_DIM 512
#define A_DIM 8
#define AH 64
#define ZH 512
#define NNEG 99
#define INV_T 10.0f

typedef __attribute__((ext_vector_type(8))) short short8;   // 8 bf16 (16 B)
typedef __attribute__((ext_vector_type(4))) float f32x4;

// fp32 -> bf16 round-to-nearest-even (unbiased; rel err <= 2^-9)
__device__ __forceinline__ short bf16rn(float x) {
    unsigned u = __float_as_uint(x);
    u += 0x7fffu + ((u >> 16) & 1u);
    return (short)(u >> 16);
}
__device__ __forceinline__ void cvt8rn(float4 x0, float4 x1, short8& h) {
    h[0] = bf16rn(x0.x); h[1] = bf16rn(x0.y); h[2] = bf16rn(x0.z); h[3] = bf16rn(x0.w);
    h[4] = bf16rn(x1.x); h[5] = bf16rn(x1.y); h[6] = bf16rn(x1.z); h[7] = bf16rn(x1.w);
}

// XOR-swizzled 16B-unit index into a [64 rows][8 units] bf16 tile (no padding).
__device__ __forceinline__ int sw(int m, int kb) { return m * 8 + (kb ^ (m & 7)); }

// ---------------------------------------------------------------------------
// prep: blocks [0,72) transpose W1 [576][512] -> W1T [512][576];
//       blocks [72,88) compute ha = relu(actions@Wa+ba)  [1024][64];
//       block 0 resets cnt.
__global__ __launch_bounds__(256) void prep_kernel(
    const float* __restrict__ W1, const float* __restrict__ actions,
    const float* __restrict__ Wa, const float* __restrict__ ba,
    float* __restrict__ W1T, float* __restrict__ ha, unsigned* __restrict__ cnt)
{
    const int id = blockIdx.x, tid = threadIdx.x;
    if (id == 0 && tid == 0) atomicExch(cnt, 0u);
    if (id < 72) {
        __shared__ float L[64][68];
        int kt = id >> 3, nt = id & 7;
#pragma unroll
        for (int i = 0; i < 4; ++i) {
            int f = tid + i * 256;
            int r = f >> 4, c4 = (f & 15) << 2;
            *(float4*)&L[r][c4] = *(const float4*)&W1[(kt * 64 + r) * 512 + nt * 64 + c4];
        }
        __syncthreads();
#pragma unroll
        for (int i = 0; i < 4; ++i) {
            int f = tid + i * 256;
            int r = f >> 4, c4 = (f & 15) << 2;
            float4 o = {L[c4][r], L[c4 + 1][r], L[c4 + 2][r], L[c4 + 3][r]};
            *(float4*)&W1T[(nt * 64 + r) * 576 + kt * 64 + c4] = o;
        }
    } else if (id < 88) {
        __shared__ float sWa[A_DIM * 64];
        __shared__ float sba[64];
        __shared__ float sact[64][A_DIM];
        int j0 = (id - 72) * 64;
        for (int i = tid; i < A_DIM * 64; i += 256) sWa[i] = Wa[i];
        if (tid < 64) sba[tid] = ba[tid];
        for (int i = tid; i < 64 * A_DIM; i += 256) (&sact[0][0])[i] = actions[j0 * A_DIM + i];
        __syncthreads();
        int r = tid >> 2, c0 = (tid & 3) * 16;
        float o[16];
#pragma unroll
        for (int c = 0; c < 16; ++c) o[c] = sba[c0 + c];
#pragma unroll
        for (int k = 0; k < A_DIM; ++k) {
            float a = sact[r][k];
#pragma unroll
            for (int c = 0; c < 16; ++c) o[c] += a * sWa[k * 64 + c0 + c];
        }
#pragma unroll
        for (int c = 0; c < 16; c += 4) {
            float4 v4 = {fmaxf(o[c], 0.f), fmaxf(o[c + 1], 0.f),
                         fmaxf(o[c + 2], 0.f), fmaxf(o[c + 3], 0.f)};
            *(float4*)&ha[(j0 + r) * 64 + c0 + c] = v4;
        }
    }
}

// ---------------------------------------------------------------------------
// Uniform NT MFMA GEMM, 640 blocks, plain bf16 (RN conversion at staging):
//   seg0 [  0,256): sim = z_next @ z_next_hat^T [1024x1024 K=512]
//   seg1 [256,384): u   = z @ W1T[:, :512]^T+b1 [1024x512  K=512]
//   seg2 [384,512): v   = z_next @ W2^T         [1024x512  K=512]
//   seg3 [512,640): g   = ha @ W1T[:,512:]^T    [1024x512  K=64]
__global__ __launch_bounds__(256) void mm_kernel(
    const float* __restrict__ z, const float* __restrict__ z_next,
    const float* __restrict__ z_next_hat, const float* __restrict__ W1T,
    const float* __restrict__ b1, const float* __restrict__ W2,
    const float* __restrict__ ha,
    float* __restrict__ sim, float* __restrict__ u, float* __restrict__ v,
    float* __restrict__ g)
{
    __shared__ short Ah[4096], Bh[4096];   // 16 KB

    const int id = blockIdx.x;
    const int tid = threadIdx.x;

    const float* Aop; const float* Bop; const float* bias = nullptr;
    float* C; int N, K, lda, ldb, bm0, bn0;
    if (id < 256) {
        int t = id; bn0 = (t & 15) * 64; bm0 = (t >> 4) * 64;
        Aop = z_next; lda = 512; Bop = z_next_hat; ldb = 512;
        C = sim; N = 1024; K = 512;
    } else if (id < 384) {
        int t = id - 256; bn0 = (t & 7) * 64; bm0 = (t >> 3) * 64;
        Aop = z; lda = 512; Bop = W1T; ldb = 576;
        C = u; N = 512; K = 512; bias = b1;
    } else if (id < 512) {
        int t = id - 384; bn0 = (t & 7) * 64; bm0 = (t >> 3) * 64;
        Aop = z_next; lda = 512; Bop = W2; ldb = 512;
        C = v; N = 512; K = 512;
    } else {
        int t = id - 512; bn0 = (t & 7) * 64; bm0 = (t >> 3) * 64;
        Aop = ha; lda = 64; Bop = W1T + 512; ldb = 576;
        C = g; N = 512; K = 64;
    }

    const int lane = tid & 63, wv = tid >> 6;
    const int lm = lane & 15, lq = lane >> 4;
    const int wm = (wv >> 1) * 32, wn = (wv & 1) * 32;
    const int sr = tid >> 2, sq = tid & 3;     // staging: row, 16-float quarter
    short8* Ah8 = (short8*)Ah; short8* Bh8 = (short8*)Bh;
    f32x4 acc[2][2] = {};

    for (int k0 = 0; k0 < K; k0 += 64) {
        {   // A: 16 consecutive floats of row sr -> units 2sq, 2sq+1
            const float* base = &Aop[(bm0 + sr) * lda + k0 + sq * 16];
            float4 x0 = *(const float4*)(base + 0), x1 = *(const float4*)(base + 4);
            float4 x2 = *(const float4*)(base + 8), x3 = *(const float4*)(base + 12);
            short8 h;
            cvt8rn(x0, x1, h); Ah8[sw(sr, 2 * sq)] = h;
            cvt8rn(x2, x3, h); Ah8[sw(sr, 2 * sq + 1)] = h;
        }
        {   // B: same, NT layout
            const float* base = &Bop[(bn0 + sr) * ldb + k0 + sq * 16];
            float4 x0 = *(const float4*)(base + 0), x1 = *(const float4*)(base + 4);
            float4 x2 = *(const float4*)(base + 8), x3 = *(const float4*)(base + 12);
            short8 h;
            cvt8rn(x0, x1, h); Bh8[sw(sr, 2 * sq)] = h;
            cvt8rn(x2, x3, h); Bh8[sw(sr, 2 * sq + 1)] = h;
        }
        __syncthreads();
#pragma unroll
        for (int kk = 0; kk < 64; kk += 32) {
            int kbi = (kk >> 3) + lq;
            short8 ah[2], bh[2];
#pragma unroll
            for (int i = 0; i < 2; ++i) {
                ah[i] = Ah8[sw(wm + i * 16 + lm, kbi)];
                bh[i] = Bh8[sw(wn + i * 16 + lm, kbi)];
            }
#pragma unroll
            for (int i = 0; i < 2; ++i)
#pragma unroll
                for (int j = 0; j < 2; ++j)
                    acc[i][j] = __builtin_amdgcn_mfma_f32_16x16x32_bf16(ah[i], bh[j], acc[i][j], 0, 0, 0);
        }
        __syncthreads();
    }
    // epilogue: C layout col=lane&15, row=(lane>>4)*4+reg
#pragma unroll
    for (int i = 0; i < 2; ++i)
#pragma unroll
        for (int j = 0; j < 2; ++j) {
            int n = bn0 + wn + j * 16 + lm;
            float bb = bias ? bias[n] : 0.0f;
#pragma unroll
            for (int r = 0; r < 4; ++r) {
                int m = bm0 + wm + i * 16 + lq * 4 + r;
                C[m * N + n] = acc[i][j][r] + bb;
            }
        }
}

// ---------------------------------------------------------------------------
// 256 blocks x 256 threads, 4 rows/block (1 row per wave) — the measured-best
// R6 structure: g-rows staged once per block in batches of 8 (single buffer),
// 8 independent dot-chains per wave. Phase 2: per-wave softmax/rank.
// Last block finalizes.
__global__ __launch_bounds__(256) void row2_kernel(
    const float* __restrict__ sim, const float* __restrict__ u,
    const float* __restrict__ v, const float* __restrict__ g,
    const float* __restrict__ z, const float* __restrict__ z_next,
    const float* __restrict__ b2,
    float* __restrict__ pw, unsigned* __restrict__ cnt, float* __restrict__ out)
{
    const int blk = blockIdx.x;
    const int tid = threadIdx.x;
    const int w = tid >> 6, lane = tid & 63;
    const int b = blk * 4 + w;
    __shared__ float gbuf[8][512];
    __shared__ float rn[4][100];
    __shared__ float sacc[4][4];
    __shared__ float red[256];
    __shared__ int sdone;

    float4 ua = *(const float4*)&u[b * 512 + lane * 4];
    float4 ub = *(const float4*)&u[b * 512 + 256 + lane * 4];
    float4 va = *(const float4*)&v[b * 512 + lane * 4];
    float4 vb = *(const float4*)&v[b * 512 + 256 + lane * 4];

    // c0 = (z[b]+b2) . z_next[b]
    float p;
    {
        float4 za = *(const float4*)&z[b * 512 + lane * 4];
        float4 zb = *(const float4*)&z[b * 512 + 256 + lane * 4];
        float4 na = *(const float4*)&z_next[b * 512 + lane * 4];
        float4 nb = *(const float4*)&z_next[b * 512 + 256 + lane * 4];
        float4 ca = *(const float4*)&b2[lane * 4];
        float4 cb = *(const float4*)&b2[256 + lane * 4];
        p  = (za.x + ca.x) * na.x + (za.y + ca.y) * na.y + (za.z + ca.z) * na.z + (za.w + ca.w) * na.w;
        p += (zb.x + cb.x) * nb.x + (zb.y + cb.y) * nb.y + (zb.z + cb.z) * nb.z + (zb.w + cb.w) * nb.w;
    }
    for (int off = 32; off; off >>= 1) p += __shfl_down(p, off);
    const float c0 = __shfl(p, 0);

    const int J0 = blk * 4;                // jr = J0 + 1 + idx, idx in [0,102)
    for (int it = 0; it < 13; ++it) {
#pragma unroll
        for (int ph = 0; ph < 4; ++ph) {   // stage up to 8 g rows
            int f4i = tid + ph * 256;
            int row = f4i >> 7, c = f4i & 127;
            int idx = it * 8 + row;
            if (idx < 102) {
                int jr = (J0 + 1 + idx) & (B_SZ - 1);
                *(float4*)&gbuf[row][c * 4] = *(const float4*)&g[jr * 512 + c * 4];
            }
        }
        __syncthreads();
        float d[8];
#pragma unroll
        for (int ri = 0; ri < 8; ++ri) {
            float4 g0 = *(const float4*)&gbuf[ri][lane * 4];
            float4 g1 = *(const float4*)&gbuf[ri][256 + lane * 4];
            float t = 0.0f;
            t += fmaxf(ua.x + g0.x, 0.0f) * va.x;
            t += fmaxf(ua.y + g0.y, 0.0f) * va.y;
            t += fmaxf(ua.z + g0.z, 0.0f) * va.z;
            t += fmaxf(ua.w + g0.w, 0.0f) * va.w;
            t += fmaxf(ub.x + g1.x, 0.0f) * vb.x;
            t += fmaxf(ub.y + g1.y, 0.0f) * vb.y;
            t += fmaxf(ub.z + g1.z, 0.0f) * vb.z;
            t += fmaxf(ub.w + g1.w, 0.0f) * vb.w;
            d[ri] = t;
        }
        for (int off = 32; off; off >>= 1) {
#pragma unroll
            for (int ri = 0; ri < 8; ++ri) d[ri] += __shfl_down(d[ri], off);
        }
        if (lane == 0) {
#pragma unroll
            for (int ri = 0; ri < 8; ++ri) {
                int idx = it * 8 + ri;
                int s1 = idx - w;              // s-1 for this wave's row
                if (idx < 102 && s1 >= 0 && s1 < 99) rn[w][s1] = c0 + d[ri];
            }
        }
        __syncthreads();
    }

    // -------- phase 2: per-wave softmax + rank on row b --------
    float4 sv[4];
#pragma unroll
    for (int i = 0; i < 4; ++i)
        sv[i] = *(const float4*)&sim[b * 1024 + lane * 16 + i * 4];
    float nva = rn[w][lane];
    float nvb = (lane < 35) ? rn[w][lane + 64] : -3.4e38f;
    float diag = sim[b * 1024 + b];

    float m = fmaxf(nva, nvb);
#pragma unroll
    for (int i = 0; i < 4; ++i)
        m = fmaxf(m, fmaxf(fmaxf(sv[i].x, sv[i].y), fmaxf(sv[i].z, sv[i].w)));
    for (int off = 32; off; off >>= 1) m = fmaxf(m, __shfl_xor(m, off));

    float es = 0.0f; int ck = 0;
#pragma unroll
    for (int i = 0; i < 4; ++i) {
        float xs[4] = {sv[i].x, sv[i].y, sv[i].z, sv[i].w};
#pragma unroll
        for (int c = 0; c < 4; ++c) {
            int j = lane * 16 + i * 4 + c;
            float x = xs[c];
            es += __expf((x - m) * INV_T);
            if (x > diag) ck++;
            else if (j < b && x == diag) ck++;   // tie-break: lower index wins
        }
    }
    es += __expf((nva - m) * INV_T);
    if (nva > diag) ck++;
    if (lane < 35) {
        es += __expf((nvb - m) * INV_T);
        if (nvb > diag) ck++;
    }
    for (int off = 32; off; off >>= 1) {
        es += __shfl_down(es, off);
        ck += __shfl_down(ck, off);
    }
    if (lane == 0) {
        float loss_b = (m - diag) * INV_T + logf(es);
        sacc[w][0] = loss_b;
        sacc[w][1] = (ck < 1) ? 1.0f : 0.0f;
        sacc[w][2] = (ck < 3) ? 1.0f : 0.0f;
        sacc[w][3] = (ck < 10) ? 1.0f : 0.0f;
    }
    __syncthreads();
    if (tid == 0) {
#pragma unroll
        for (int c = 0; c < 4; ++c)
            pw[blk * 4 + c] = sacc[0][c] + sacc[1][c] + sacc[2][c] + sacc[3][c];
        __threadfence();
        unsigned old = atomicAdd(cnt, 1u);
        sdone = (old == 255u) ? 1 : 0;
    }
    __syncthreads();
    if (sdone) {
        __threadfence();
        int c = tid & 3;
        float s = 0.0f;
        for (int r = tid >> 2; r < 256; r += 64) s += pw[r * 4 + c];
        red[tid] = s;
        __syncthreads();
        if (tid < 4) {
            float t = 0.0f;
            for (int q = 0; q < 64; ++q) t += red[tid + q * 4];
            out[tid] = t * (1.0f / (float)B_SZ);
        }
    }
}

// ---------------------------------------------------------------------------
extern "C" void kernel_launch(void* const* d_in, const int* in_sizes, int n_in,
                              void* d_out, int out_size, void* d_ws, size_t ws_size,
                              hipStream_t stream) {
    const float* z          = (const float*)d_in[0];
    const float* z_next     = (const float*)d_in[1];
    const float* z_next_hat = (const float*)d_in[2];
    const float* actions    = (const float*)d_in[3];
    const float* Wa         = (const float*)d_in[4];
    const float* ba         = (const float*)d_in[5];
    const float* W1         = (const float*)d_in[6];
    const float* b1         = (const float*)d_in[7];
    const float* W2         = (const float*)d_in[8];
    const float* b2         = (const float*)d_in[9];
    float* out = (float*)d_out;

    float* ws   = (float*)d_ws;
    float* sim  = ws;                          // 1024*1024
    float* u    = sim + B_SZ * B_SZ;           // 1024*512
    float* v    = u + B_SZ * ZH;               // 1024*512
    float* g    = v + B_SZ * ZH;               // 1024*512
    float* W1T  = g + B_SZ * ZH;               // 512*576
    float* ha   = W1T + 512 * 576;             // 1024*64
    float* pw   = ha + B_SZ * AH;              // 256*4
    unsigned* cnt = (unsigned*)(pw + 256 * 4);

    prep_kernel<<<88, 256, 0, stream>>>(W1, actions, Wa, ba, W1T, ha, cnt);
    mm_kernel<<<640, 256, 0, stream>>>(z, z_next, z_next_hat, W1T, b1, W2, ha,
                                       sim, u, v, g);
    row2_kernel<<<256, 256, 0, stream>>>(sim, u, v, g, z, z_next, b2, pw, cnt, out);
}